// Round 4
// baseline (775.376 us; speedup 1.0000x reference)
//
#include <hip/hip_runtime.h>
#include <math.h>

// Problem constants (from reference)
#define Nn 50000
#define Ee 500000
#define Cc 256
#define Hh 128
#define Ll 4
#define Gg 64
#define Kk 8
#define NCc 2

#define NB 196       // ceil(Nn/256)
#define GY 391       // ceil(Nn/128)

typedef __attribute__((ext_vector_type(8))) short short8;
typedef __attribute__((ext_vector_type(4))) float f32x4;

__device__ __forceinline__ unsigned short f2bf(float f) {
    union { float f; unsigned int u; } v;
    v.f = f;
    unsigned int u = v.u;
    return (unsigned short)((u + 0x7FFFu + ((u >> 16) & 1u)) >> 16);
}
__device__ __forceinline__ float bf2f(unsigned short s) {
    union { float f; unsigned int u; } v;
    v.u = ((unsigned int)s) << 16;
    return v.f;
}

// ---------------- CSR build ----------------

__global__ void hist_kernel(const int* __restrict__ dst, int* __restrict__ deg) {
    int e = blockIdx.x * 256 + threadIdx.x;
    if (e < Ee) atomicAdd(&deg[dst[e]], 1);
}

__global__ __launch_bounds__(256) void bsum_kernel(const int* __restrict__ deg,
                                                   int* __restrict__ bsum) {
    __shared__ int ws[4];
    int t = threadIdx.x;
    int i = blockIdx.x * 256 + t;
    int v = (i < Nn) ? deg[i] : 0;
#pragma unroll
    for (int o = 32; o; o >>= 1) v += __shfl_down(v, o, 64);
    if ((t & 63) == 0) ws[t >> 6] = v;
    __syncthreads();
    if (t == 0) bsum[blockIdx.x] = ws[0] + ws[1] + ws[2] + ws[3];
}

__global__ __launch_bounds__(256) void bscan_kernel(const int* __restrict__ bsum,
                                                    int* __restrict__ boff,
                                                    int* __restrict__ off) {
    __shared__ int sc[256];
    int t = threadIdx.x;
    int v = (t < NB) ? bsum[t] : 0;
    sc[t] = v;
    __syncthreads();
    for (int o = 1; o < 256; o <<= 1) {
        int u = (t >= o) ? sc[t - o] : 0;
        __syncthreads();
        sc[t] += u;
        __syncthreads();
    }
    if (t < NB) boff[t] = sc[t] - v;  // exclusive
    if (t == NB - 1) off[Nn] = sc[t];
}

__global__ __launch_bounds__(256) void offsets_kernel(const int* __restrict__ deg,
                                                      const int* __restrict__ boff,
                                                      int* __restrict__ off,
                                                      int* __restrict__ pos) {
    __shared__ int sc[256];
    int t = threadIdx.x;
    int i = blockIdx.x * 256 + t;
    int v = (i < Nn) ? deg[i] : 0;
    sc[t] = v;
    __syncthreads();
    for (int o = 1; o < 256; o <<= 1) {
        int u = (t >= o) ? sc[t - o] : 0;
        __syncthreads();
        sc[t] += u;
        __syncthreads();
    }
    int excl = sc[t] - v + boff[blockIdx.x];
    if (i < Nn) {
        off[i] = excl;
        pos[i] = excl;
    }
}

__global__ void scatter_kernel(const int* __restrict__ src, const int* __restrict__ dst,
                               const float* __restrict__ attr, int* __restrict__ pos,
                               int* __restrict__ ssrc, float* __restrict__ sattr) {
    int e = blockIdx.x * 256 + threadIdx.x;
    if (e < Ee) {
        int d = dst[e];
        int p = atomicAdd(&pos[d], 1);
        ssrc[p] = src[e];
        sattr[p] = attr[e];
    }
}

// ---------------- weight convert + transpose to bf16 [N][K] ----------------
// wt layout: [0, 65536)       proj  [256 n][256 k]  (n<128: lin_src col, else lin_dst)
//            [65536, 196608)  w1[l] [256 n][128 k]
//            [196608, 327680) w2[l] [128 n][256 k]

__global__ void wconv_kernel(const float* __restrict__ lin_src_w,
                             const float* __restrict__ lin_dst_w,
                             const float* __restrict__ mlp_w1,
                             const float* __restrict__ mlp_w2,
                             unsigned short* __restrict__ wt) {
    int idx = blockIdx.x * 256 + threadIdx.x;
    if (idx >= 327680) return;
    float val;
    if (idx < 65536) {
        int n = idx >> 8, k = idx & 255;
        val = (n < 128) ? lin_src_w[k * 128 + n] : lin_dst_w[k * 128 + (n - 128)];
    } else if (idx < 196608) {
        int r = idx - 65536;
        int l = r >> 15, e = r & 32767;
        int n = e >> 7, k = e & 127;
        val = mlp_w1[(size_t)l * 32768 + k * 256 + n];
    } else {
        int r = idx - 196608;
        int l = r >> 15, e = r & 32767;
        int n = e >> 8, k = e & 255;
        val = mlp_w2[(size_t)l * 32768 + k * 128 + n];
    }
    wt[idx] = f2bf(val);
}

// ---------------- bf16 MFMA GEMM, 128x128 tile, fragment-order LDS ----------------
// C[M,N] = A[M,K] @ Bt[N][K].  LDS layout: unit16(tile,quad,lrow) = (tile*4+quad)*16+lrow
// -> both staging writes and fragment ds_read_b128 are quad-contiguous (<=2-way, free).
// mode 0: OutB = bf16(v)                       (proj; bias2 covers cols >= 128)
// mode 1: OutB = bf16(relu(bn(v)))             (w1 + mlp-BN)
// mode 2: h = v;        Hbuf = h; OutB = bf16(relu(norm(h)))   (w2, layer 0)
// mode 3: h = Hbuf + v; Hbuf = h; OutB = bf16(relu(norm(h)))   (w2, mid layers)
// mode 4: h = Hbuf + v;           OutB = bf16(relu(norm(h)))   (w2, last layer)

#define BM 128
#define BN2 128
#define BK 32

template <bool AF32>
__global__ __launch_bounds__(256) void gemm_kernel(
    const void* __restrict__ Aptr, const unsigned short* __restrict__ Bt,
    const float* __restrict__ bias, const float* __restrict__ bias2,
    const float* __restrict__ g_, const float* __restrict__ b_,
    const float* __restrict__ m_, const float* __restrict__ v_,
    float* __restrict__ Hbuf, unsigned short* __restrict__ OutB,
    int M, int N, int K, int mode) {
    __shared__ __align__(16) unsigned short As[BM * BK];   // 8 KB
    __shared__ __align__(16) unsigned short Bs[BN2 * BK];  // 8 KB
    int tid = threadIdx.x;
    int m0 = blockIdx.y * BM, n0 = blockIdx.x * BN2;
    int wave = tid >> 6, lane = tid & 63;
    int wr = wave >> 1, wc = wave & 1;  // 2x2 wave grid, 64x64 per wave
    int lrow = lane & 15, quad = lane >> 4;

    f32x4 acc[4][4];
#pragma unroll
    for (int i = 0; i < 4; i++)
#pragma unroll
        for (int j = 0; j < 4; j++) acc[i][j] = (f32x4){0.f, 0.f, 0.f, 0.f};

    for (int k0 = 0; k0 < K; k0 += BK) {
        // ---- stage A: 128 rows x 32 k, 2 passes of 256 threads x 8 elems ----
#pragma unroll
        for (int it = 0; it < 2; it++) {
            int fi = tid + it * 256;
            int row = fi >> 2, q = fi & 3;
            int gr = m0 + row;
            int lidx = (((row >> 4) * 4 + q) * 16 + (row & 15)) * 8;
            if (AF32) {
                unsigned short tmp[8];
                if (gr < M) {
                    const float* ap = (const float*)Aptr + (size_t)gr * K + k0 + q * 8;
                    float4 v0 = ((const float4*)ap)[0];
                    float4 v1 = ((const float4*)ap)[1];
                    tmp[0] = f2bf(v0.x); tmp[1] = f2bf(v0.y);
                    tmp[2] = f2bf(v0.z); tmp[3] = f2bf(v0.w);
                    tmp[4] = f2bf(v1.x); tmp[5] = f2bf(v1.y);
                    tmp[6] = f2bf(v1.z); tmp[7] = f2bf(v1.w);
                } else {
#pragma unroll
                    for (int i = 0; i < 8; i++) tmp[i] = 0;
                }
                *(short8*)&As[lidx] = *(short8*)&tmp[0];
            } else {
                short8 v = (short8){0, 0, 0, 0, 0, 0, 0, 0};
                if (gr < M)
                    v = *(const short8*)((const unsigned short*)Aptr + (size_t)gr * K + k0 + q * 8);
                *(short8*)&As[lidx] = v;
            }
        }
        // ---- stage B: 128 n-rows x 32 k ----
#pragma unroll
        for (int it = 0; it < 2; it++) {
            int fi = tid + it * 256;
            int row = fi >> 2, q = fi & 3;
            int lidx = (((row >> 4) * 4 + q) * 16 + (row & 15)) * 8;
            *(short8*)&Bs[lidx] = *(const short8*)(Bt + (size_t)(n0 + row) * K + k0 + q * 8);
        }
        __syncthreads();
        short8 af[4], bf[4];
#pragma unroll
        for (int mt = 0; mt < 4; mt++)
            af[mt] = *(const short8*)&As[(((wr * 4 + mt) * 4 + quad) * 16 + lrow) * 8];
#pragma unroll
        for (int nt = 0; nt < 4; nt++)
            bf[nt] = *(const short8*)&Bs[(((wc * 4 + nt) * 4 + quad) * 16 + lrow) * 8];
#pragma unroll
        for (int mt = 0; mt < 4; mt++)
#pragma unroll
            for (int nt = 0; nt < 4; nt++)
                acc[mt][nt] = __builtin_amdgcn_mfma_f32_16x16x32_bf16(af[mt], bf[nt],
                                                                     acc[mt][nt], 0, 0, 0);
        __syncthreads();
    }

    // ---- epilogue ----
#pragma unroll
    for (int nt = 0; nt < 4; nt++) {
        int gc = n0 + wc * 64 + nt * 16 + lrow;
        float bs = bias2 ? ((gc < 128) ? bias[gc] : bias2[gc - 128]) : bias[gc];
        float g = 0.f, bb = 0.f, mm = 0.f, inv = 0.f;
        if (mode >= 1) {
            g = g_[gc];
            bb = b_[gc];
            mm = m_[gc];
            inv = rsqrtf(v_[gc] + 1e-5f);
        }
#pragma unroll
        for (int mt = 0; mt < 4; mt++) {
#pragma unroll
            for (int r = 0; r < 4; r++) {
                int gr = m0 + wr * 64 + mt * 16 + quad * 4 + r;
                if (gr < M) {
                    float v = acc[mt][nt][r] + bs;
                    size_t idx = (size_t)gr * N + gc;
                    if (mode == 0) {
                        OutB[idx] = f2bf(v);
                    } else if (mode == 1) {
                        OutB[idx] = f2bf(fmaxf(g * (v - mm) * inv + bb, 0.f));
                    } else {
                        float h = v + ((mode >= 3) ? Hbuf[idx] : 0.f);
                        if (mode <= 3) Hbuf[idx] = h;
                        OutB[idx] = f2bf(fmaxf(g * (h - mm) * inv + bb, 0.f));
                    }
                }
            }
        }
    }
}

// ---------------- Fused GENConv aggregation (one-pass online softmax) ----------------

__global__ __launch_bounds__(128) void agg_kernel(
    const unsigned short* __restrict__ xs, int xss,
    const unsigned short* __restrict__ xd, int xds,
    const int* __restrict__ ssrc, const float* __restrict__ sattr,
    const int* __restrict__ off,
    const float* __restrict__ ew, const float* __restrict__ eb,
    const float* __restrict__ tptr, unsigned short* __restrict__ outb) {
    int d = blockIdx.x;
    int hh = threadIdx.x;
    int s0 = off[d], s1 = off[d + 1];
    float w = ew[hh], b = eb[hh];
    float tl = tptr[0];
    float mmax = -INFINITY, denom = 0.f, num = 0.f;

#define EDGE_STEP(xv, av)                                  \
    {                                                      \
        float msg = fmaxf((xv) + (av)*w + b, 0.f) + 1e-7f; \
        float z = msg * tl;                                \
        float nm = fmaxf(mmax, z);                         \
        float c = __expf(mmax - nm);                       \
        float e = __expf(z - nm);                          \
        denom = denom * c + e;                             \
        num = num * c + msg * e;                           \
        mmax = nm;                                         \
    }

    int j = s0;
    for (; j + 3 < s1; j += 4) {
        int i0 = ssrc[j], i1 = ssrc[j + 1], i2 = ssrc[j + 2], i3 = ssrc[j + 3];
        float a0 = sattr[j], a1 = sattr[j + 1], a2 = sattr[j + 2], a3 = sattr[j + 3];
        float x0 = bf2f(xs[(size_t)i0 * xss + hh]);
        float x1 = bf2f(xs[(size_t)i1 * xss + hh]);
        float x2 = bf2f(xs[(size_t)i2 * xss + hh]);
        float x3 = bf2f(xs[(size_t)i3 * xss + hh]);
        EDGE_STEP(x0, a0)
        EDGE_STEP(x1, a1)
        EDGE_STEP(x2, a2)
        EDGE_STEP(x3, a3)
    }
    for (; j < s1; j++) {
        int s = ssrc[j];
        float a = sattr[j];
        float xv = bf2f(xs[(size_t)s * xss + hh]);
        EDGE_STEP(xv, a)
    }
    float agg = (s1 > s0) ? (num / fmaxf(denom, 1e-16f)) : 0.f;
    outb[(size_t)d * Hh + hh] = f2bf(agg + bf2f(xd[(size_t)d * xds + hh]));
#undef EDGE_STEP
}

// ---------------- mean-pool over pre-normed bf16 ----------------

#define PCHUNK 100

__global__ __launch_bounds__(128) void pool_kernel(
    const unsigned short* __restrict__ hb, const int* __restrict__ batch,
    float* __restrict__ pooled, float* __restrict__ cnt) {
    int hh = threadIdx.x;
    int i0 = blockIdx.x * PCHUNK;
    int i1 = min(i0 + PCHUNK, Nn);
    if (i0 >= Nn) return;
    int cur = batch[i0];
    float sum = 0.f, c = 0.f;
    for (int i = i0; i < i1; i++) {
        int gid = batch[i];
        float val = bf2f(hb[(size_t)i * Hh + hh]);
        if (gid != cur) {
            atomicAdd(&pooled[(size_t)cur * Hh + hh], sum);
            if (hh == 0) atomicAdd(&cnt[cur], c);
            cur = gid;
            sum = 0.f;
            c = 0.f;
        }
        sum += val;
        c += 1.f;
    }
    atomicAdd(&pooled[(size_t)cur * Hh + hh], sum);
    if (hh == 0) atomicAdd(&cnt[cur], c);
}

// ---------------- classifier ----------------

__global__ __launch_bounds__(128) void cls_kernel(const float* __restrict__ pooled,
                                                  const float* __restrict__ cnt,
                                                  const float* __restrict__ clinical,
                                                  const float* __restrict__ w,
                                                  const float* __restrict__ bias,
                                                  float* __restrict__ out) {
    int t = threadIdx.x;
    int g = t >> 1, c = t & 1;
    float inv = 1.f / fmaxf(cnt[g], 1.f);
    float s = bias[c];
    for (int j = 0; j < Hh; j++) s += pooled[g * Hh + j] * inv * w[j * NCc + c];
    for (int k = 0; k < Kk; k++) s += clinical[g * Kk + k] * w[(Hh + k) * NCc + c];
    out[g * NCc + c] = s;
}

// ---------------- launch ----------------

extern "C" void kernel_launch(void* const* d_in, const int* in_sizes, int n_in,
                              void* d_out, int out_size, void* d_ws, size_t ws_size,
                              hipStream_t stream) {
    const float* x = (const float*)d_in[0];
    const int* eidx = (const int*)d_in[1];
    const float* eattr = (const float*)d_in[2];
    const int* batch = (const int*)d_in[3];
    const float* clinical = (const float*)d_in[4];
    const float* lin_src_b = (const float*)d_in[6];
    const float* lin_dst_b = (const float*)d_in[8];
    const float* edge_w = (const float*)d_in[9];
    const float* edge_b = (const float*)d_in[10];
    const float* tt = (const float*)d_in[11];
    const float* mlp_b1 = (const float*)d_in[13];
    const float* bn_g = (const float*)d_in[14];
    const float* bn_b = (const float*)d_in[15];
    const float* bn_m = (const float*)d_in[16];
    const float* bn_v = (const float*)d_in[17];
    const float* mlp_b2 = (const float*)d_in[19];
    const float* norm_g = (const float*)d_in[20];
    const float* norm_b = (const float*)d_in[21];
    const float* norm_m = (const float*)d_in[22];
    const float* norm_v = (const float*)d_in[23];
    const float* cls_w = (const float*)d_in[24];
    const float* cls_b = (const float*)d_in[25];
    float* out = (float*)d_out;

    const int* src = eidx;
    const int* dst = eidx + Ee;

    char* ws = (char*)d_ws;
    size_t off_b = 0;
    auto alloc = [&](size_t bytes) -> void* {
        void* p = ws + off_b;
        off_b += (bytes + 255) & ~(size_t)255;
        return p;
    };
    unsigned short* xsd = (unsigned short*)alloc((size_t)Nn * 256 * 2);
    unsigned short* rbuf = (unsigned short*)alloc((size_t)Nn * Hh * 2);
    unsigned short* aggout = (unsigned short*)alloc((size_t)Nn * Hh * 2);
    unsigned short* hmid = (unsigned short*)alloc((size_t)Nn * 2 * Hh * 2);
    unsigned short* pnorm = (unsigned short*)alloc((size_t)Nn * Hh * 2);
    float* hbuf = (float*)alloc((size_t)Nn * Hh * 4);
    int* deg = (int*)alloc((Nn + 1) * 4);
    int* offp = (int*)alloc((Nn + 1) * 4);
    int* pos = (int*)alloc((size_t)Nn * 4);
    int* bsum = (int*)alloc(NB * 4);
    int* boff = (int*)alloc(NB * 4);
    int* ssrc = (int*)alloc((size_t)Ee * 4);
    float* sattr = (float*)alloc((size_t)Ee * 4);
    float* pooled = (float*)alloc((size_t)Gg * Hh * 4);
    float* cntb = (float*)alloc(Gg * 4);
    unsigned short* wt = (unsigned short*)alloc((size_t)327680 * 2);

    hipMemsetAsync(deg, 0, (Nn + 1) * 4, stream);
    hipMemsetAsync(pooled, 0, (size_t)Gg * Hh * 4, stream);
    hipMemsetAsync(cntb, 0, Gg * 4, stream);

    hist_kernel<<<(Ee + 255) / 256, 256, 0, stream>>>(dst, deg);
    bsum_kernel<<<NB, 256, 0, stream>>>(deg, bsum);
    bscan_kernel<<<1, 256, 0, stream>>>(bsum, boff, offp);
    offsets_kernel<<<NB, 256, 0, stream>>>(deg, boff, offp, pos);
    scatter_kernel<<<(Ee + 255) / 256, 256, 0, stream>>>(src, dst, eattr, pos, ssrc, sattr);
    wconv_kernel<<<1280, 256, 0, stream>>>((const float*)d_in[5], (const float*)d_in[7],
                                           (const float*)d_in[12], (const float*)d_in[18], wt);

    const unsigned short* wt_proj = wt;
    const unsigned short* wt_w1 = wt + 65536;
    const unsigned short* wt_w2 = wt + 196608;

    // Fused projection: xsd[:, :128] = x@Wsrc+b, xsd[:, 128:] = x@Wdst+b
    gemm_kernel<true><<<dim3(2, GY), 256, 0, stream>>>(
        x, wt_proj, lin_src_b, lin_dst_b, nullptr, nullptr, nullptr, nullptr, nullptr, xsd,
        Nn, 256, Cc, 0);

    for (int l = 0; l < Ll; l++) {
        const unsigned short* cxs;
        const unsigned short* cxd;
        int xss, xds;
        if (l == 0) {
            cxs = xsd;
            xss = 256;
            cxd = xsd + 128;
            xds = 256;
        } else {
            cxs = rbuf;
            xss = Hh;
            cxd = rbuf;
            xds = Hh;
        }
        agg_kernel<<<Nn, 128, 0, stream>>>(cxs, xss, cxd, xds, ssrc, sattr, offp,
                                           edge_w + l * Hh, edge_b + l * Hh, tt + l, aggout);
        // w1: [N,128] @ [128,256] -> hmid (mlp-BN + ReLU, bf16)
        gemm_kernel<false><<<dim3(2, GY), 256, 0, stream>>>(
            aggout, wt_w1 + (size_t)l * 32768, mlp_b1 + l * 2 * Hh, nullptr,
            bn_g + l * 2 * Hh, bn_b + l * 2 * Hh, bn_m + l * 2 * Hh, bn_v + l * 2 * Hh,
            nullptr, hmid, Nn, 2 * Hh, Hh, 1);
        // w2: [N,256] @ [256,128]; fused residual + next-layer (or final) norm
        int nl = (l == Ll - 1) ? 0 : (l + 1);
        int mode = (l == 0) ? 2 : ((l == Ll - 1) ? 4 : 3);
        unsigned short* outB = (l == Ll - 1) ? pnorm : rbuf;
        gemm_kernel<false><<<dim3(1, GY), 256, 0, stream>>>(
            hmid, wt_w2 + (size_t)l * 32768, mlp_b2 + l * Hh, nullptr,
            norm_g + nl * Hh, norm_b + nl * Hh, norm_m + nl * Hh, norm_v + nl * Hh,
            hbuf, outB, Nn, Hh, 2 * Hh, mode);
    }

    pool_kernel<<<(Nn + PCHUNK - 1) / PCHUNK, 128, 0, stream>>>(pnorm, batch, pooled, cntb);
    cls_kernel<<<1, 128, 0, stream>>>(pooled, cntb, clinical, cls_w, cls_b, out);
}

// Round 5
// 700.364 us; speedup vs baseline: 1.1071x; 1.1071x over previous
//
#include <hip/hip_runtime.h>
#include <math.h>

// Problem constants (from reference)
#define Nn 50000
#define Ee 500000
#define Cc 256
#define Hh 128
#define Ll 4
#define Gg 64
#define Kk 8
#define NCc 2

#define NB 196  // ceil(Nn/256)
#define GY 391  // ceil(Nn/128)

typedef __attribute__((ext_vector_type(8))) short short8;
typedef __attribute__((ext_vector_type(4))) float f32x4;

__device__ __forceinline__ unsigned short f2bf(float f) {
    union { float f; unsigned int u; } v;
    v.f = f;
    unsigned int u = v.u;
    return (unsigned short)((u + 0x7FFFu + ((u >> 16) & 1u)) >> 16);
}
__device__ __forceinline__ float bf2f(unsigned short s) {
    union { float f; unsigned int u; } v;
    v.u = ((unsigned int)s) << 16;
    return v.f;
}

// ---------------- CSR build ----------------

__global__ void hist_kernel(const int* __restrict__ dst, int* __restrict__ deg) {
    int e = blockIdx.x * 256 + threadIdx.x;
    if (e < Ee) atomicAdd(&deg[dst[e]], 1);
}

__global__ __launch_bounds__(256) void bsum_kernel(const int* __restrict__ deg,
                                                   int* __restrict__ bsum) {
    __shared__ int ws[4];
    int t = threadIdx.x;
    int i = blockIdx.x * 256 + t;
    int v = (i < Nn) ? deg[i] : 0;
#pragma unroll
    for (int o = 32; o; o >>= 1) v += __shfl_down(v, o, 64);
    if ((t & 63) == 0) ws[t >> 6] = v;
    __syncthreads();
    if (t == 0) bsum[blockIdx.x] = ws[0] + ws[1] + ws[2] + ws[3];
}

__global__ __launch_bounds__(256) void bscan_kernel(const int* __restrict__ bsum,
                                                    int* __restrict__ boff,
                                                    int* __restrict__ off) {
    __shared__ int sc[256];
    int t = threadIdx.x;
    int v = (t < NB) ? bsum[t] : 0;
    sc[t] = v;
    __syncthreads();
    for (int o = 1; o < 256; o <<= 1) {
        int u = (t >= o) ? sc[t - o] : 0;
        __syncthreads();
        sc[t] += u;
        __syncthreads();
    }
    if (t < NB) boff[t] = sc[t] - v;  // exclusive
    if (t == NB - 1) off[Nn] = sc[t];
}

__global__ __launch_bounds__(256) void offsets_kernel(const int* __restrict__ deg,
                                                      const int* __restrict__ boff,
                                                      int* __restrict__ off,
                                                      int* __restrict__ pos) {
    __shared__ int sc[256];
    int t = threadIdx.x;
    int i = blockIdx.x * 256 + t;
    int v = (i < Nn) ? deg[i] : 0;
    sc[t] = v;
    __syncthreads();
    for (int o = 1; o < 256; o <<= 1) {
        int u = (t >= o) ? sc[t - o] : 0;
        __syncthreads();
        sc[t] += u;
        __syncthreads();
    }
    int excl = sc[t] - v + boff[blockIdx.x];
    if (i < Nn) {
        off[i] = excl;
        pos[i] = excl;
    }
}

__global__ void scatter_kernel(const int* __restrict__ src, const int* __restrict__ dst,
                               const float* __restrict__ attr, int* __restrict__ pos,
                               int* __restrict__ ssrc, float* __restrict__ sattr) {
    int e = blockIdx.x * 256 + threadIdx.x;
    if (e < Ee) {
        int d = dst[e];
        int p = atomicAdd(&pos[d], 1);
        ssrc[p] = src[e];
        sattr[p] = attr[e];
    }
}

// ---------------- weight convert + transpose to bf16 [N][K] ----------------
// wt layout: [0, 65536)       proj  [256 n][256 k]  (n<128: lin_src col, else lin_dst)
//            [65536, 196608)  w1[l] [256 n][128 k]
//            [196608, 327680) w2[l] [128 n][256 k]

__global__ void wconv_kernel(const float* __restrict__ lin_src_w,
                             const float* __restrict__ lin_dst_w,
                             const float* __restrict__ mlp_w1,
                             const float* __restrict__ mlp_w2,
                             unsigned short* __restrict__ wt) {
    int idx = blockIdx.x * 256 + threadIdx.x;
    if (idx >= 327680) return;
    float val;
    if (idx < 65536) {
        int n = idx >> 8, k = idx & 255;
        val = (n < 128) ? lin_src_w[k * 128 + n] : lin_dst_w[k * 128 + (n - 128)];
    } else if (idx < 196608) {
        int r = idx - 65536;
        int l = r >> 15, e = r & 32767;
        int n = e >> 7, k = e & 127;
        val = mlp_w1[(size_t)l * 32768 + k * 256 + n];
    } else {
        int r = idx - 196608;
        int l = r >> 15, e = r & 32767;
        int n = e >> 8, k = e & 255;
        val = mlp_w2[(size_t)l * 32768 + k * 128 + n];
    }
    wt[idx] = f2bf(val);
}

// ---------------- x -> bf16 (once) ----------------

__global__ void xconv_kernel(const float* __restrict__ x, unsigned short* __restrict__ xbf) {
    int i = blockIdx.x * 256 + threadIdx.x;  // octet index, total Nn*Cc/8 = 1.6M
    if (i < Nn * Cc / 8) {
        const float4* p = (const float4*)(x + (size_t)i * 8);
        float4 a = p[0], b = p[1];
        unsigned short t[8];
        t[0] = f2bf(a.x); t[1] = f2bf(a.y); t[2] = f2bf(a.z); t[3] = f2bf(a.w);
        t[4] = f2bf(b.x); t[5] = f2bf(b.y); t[6] = f2bf(b.z); t[7] = f2bf(b.w);
        *(short8*)(xbf + (size_t)i * 8) = *(short8*)t;
    }
}

// ---------------- bf16 MFMA GEMM, 128x64 tile, BK=64, fragment-order LDS ----------------
// C[M,N] = A[M,K](bf16) @ Bt[N][K](bf16).
// LDS unit16(tile, kb, lrow): short idx = ((tile*8 + kb)*16 + lrow)*8 -- staging writes
// and fragment ds_read_b128 are both 16 B/lane contiguous per 16-lane group.
// mode 0: OutB = bf16(v)                        (proj; bias2 covers cols >= 128)
// mode 1: OutB = bf16(relu(bn(v)))              (w1 + mlp-BN)
// mode 2: h = v;        Hbuf = h; OutB = bf16(relu(norm(h)))   (w2, layer 0)
// mode 3: h = Hbuf + v; Hbuf = h; OutB = bf16(relu(norm(h)))   (w2, mid layers)
// mode 4: h = Hbuf + v;           OutB = bf16(relu(norm(h)))   (w2, last layer)

#define BM 128
#define BN 64
#define BK 64

__global__ __launch_bounds__(256) void gemm_kernel(
    const unsigned short* __restrict__ A, const unsigned short* __restrict__ Bt,
    const float* __restrict__ bias, const float* __restrict__ bias2,
    const float* __restrict__ g_, const float* __restrict__ b_,
    const float* __restrict__ m_, const float* __restrict__ v_,
    float* __restrict__ Hbuf, unsigned short* __restrict__ OutB,
    int M, int N, int K, int mode) {
    __shared__ __align__(16) unsigned short As[BM * BK];  // 16 KB
    __shared__ __align__(16) unsigned short Bs[BN * BK];  // 8 KB
    int tid = threadIdx.x;
    int m0 = blockIdx.y * BM, n0 = blockIdx.x * BN;
    int wave = tid >> 6, lane = tid & 63;
    int wr = wave >> 1, wc = wave & 1;  // 2x2 wave grid: 64 rows x 32 cols per wave
    int lrow = lane & 15, quad = lane >> 4;

    f32x4 acc[4][2];
#pragma unroll
    for (int i = 0; i < 4; i++)
#pragma unroll
        for (int j = 0; j < 2; j++) acc[i][j] = (f32x4){0.f, 0.f, 0.f, 0.f};

    for (int k0 = 0; k0 < K; k0 += BK) {
        // ---- stage A: 128 rows x 64 k = 1024 slots of 16 lanes*16 B ----
#pragma unroll
        for (int j = 0; j < 4; j++) {
            int fi = j * 256 + tid;
            int u = fi >> 4, l = fi & 15;
            int tile = u >> 3, kb = u & 7;
            int gr = m0 + tile * 16 + l;
            short8 v = (short8){0, 0, 0, 0, 0, 0, 0, 0};
            if (gr < M) v = *(const short8*)(A + (size_t)gr * K + k0 + kb * 8);
            *(short8*)&As[fi * 8] = v;
        }
        // ---- stage B: 64 n-rows x 64 k ----
#pragma unroll
        for (int j = 0; j < 2; j++) {
            int fi = j * 256 + tid;
            int u = fi >> 4, l = fi & 15;
            int tile = u >> 3, kb = u & 7;
            *(short8*)&Bs[fi * 8] =
                *(const short8*)(Bt + (size_t)(n0 + tile * 16 + l) * K + k0 + kb * 8);
        }
        __syncthreads();
#pragma unroll
        for (int s = 0; s < 2; s++) {
            short8 af[4], bf[2];
#pragma unroll
            for (int mt = 0; mt < 4; mt++)
                af[mt] = *(const short8*)&As[(((wr * 4 + mt) * 8 + s * 4 + quad) * 16 + lrow) * 8];
#pragma unroll
            for (int nt = 0; nt < 2; nt++)
                bf[nt] = *(const short8*)&Bs[(((wc * 2 + nt) * 8 + s * 4 + quad) * 16 + lrow) * 8];
#pragma unroll
            for (int mt = 0; mt < 4; mt++)
#pragma unroll
                for (int nt = 0; nt < 2; nt++)
                    acc[mt][nt] = __builtin_amdgcn_mfma_f32_16x16x32_bf16(af[mt], bf[nt],
                                                                         acc[mt][nt], 0, 0, 0);
        }
        __syncthreads();
    }

    // ---- epilogue ----
#pragma unroll
    for (int nt = 0; nt < 2; nt++) {
        int gc = n0 + wc * 32 + nt * 16 + lrow;
        float bs = bias2 ? ((gc < 128) ? bias[gc] : bias2[gc - 128]) : bias[gc];
        float g = 0.f, bb = 0.f, mm = 0.f, inv = 0.f;
        if (mode >= 1) {
            g = g_[gc];
            bb = b_[gc];
            mm = m_[gc];
            inv = rsqrtf(v_[gc] + 1e-5f);
        }
#pragma unroll
        for (int mt = 0; mt < 4; mt++) {
#pragma unroll
            for (int r = 0; r < 4; r++) {
                int gr = m0 + wr * 64 + mt * 16 + quad * 4 + r;
                if (gr < M) {
                    float v = acc[mt][nt][r] + bs;
                    size_t idx = (size_t)gr * N + gc;
                    if (mode == 0) {
                        OutB[idx] = f2bf(v);
                    } else if (mode == 1) {
                        OutB[idx] = f2bf(fmaxf(g * (v - mm) * inv + bb, 0.f));
                    } else {
                        float h = v + ((mode >= 3) ? Hbuf[idx] : 0.f);
                        if (mode <= 3) Hbuf[idx] = h;
                        OutB[idx] = f2bf(fmaxf(g * (h - mm) * inv + bb, 0.f));
                    }
                }
            }
        }
    }
}

// ---------------- Fused GENConv aggregation (one-pass online softmax) ----------------

__global__ __launch_bounds__(128) void agg_kernel(
    const unsigned short* __restrict__ xs, int xss,
    const unsigned short* __restrict__ xd, int xds,
    const int* __restrict__ ssrc, const float* __restrict__ sattr,
    const int* __restrict__ off,
    const float* __restrict__ ew, const float* __restrict__ eb,
    const float* __restrict__ tptr, unsigned short* __restrict__ outb) {
    int d = blockIdx.x;
    int hh = threadIdx.x;
    int s0 = off[d], s1 = off[d + 1];
    float w = ew[hh], b = eb[hh];
    float tl = tptr[0];
    float mmax = -INFINITY, denom = 0.f, num = 0.f;

#define EDGE_STEP(xv, av)                                  \
    {                                                      \
        float msg = fmaxf((xv) + (av)*w + b, 0.f) + 1e-7f; \
        float z = msg * tl;                                \
        float nm = fmaxf(mmax, z);                         \
        float c = __expf(mmax - nm);                       \
        float e = __expf(z - nm);                          \
        denom = denom * c + e;                             \
        num = num * c + msg * e;                           \
        mmax = nm;                                         \
    }

    int j = s0;
    for (; j + 3 < s1; j += 4) {
        int i0 = ssrc[j], i1 = ssrc[j + 1], i2 = ssrc[j + 2], i3 = ssrc[j + 3];
        float a0 = sattr[j], a1 = sattr[j + 1], a2 = sattr[j + 2], a3 = sattr[j + 3];
        float x0 = bf2f(xs[(size_t)i0 * xss + hh]);
        float x1 = bf2f(xs[(size_t)i1 * xss + hh]);
        float x2 = bf2f(xs[(size_t)i2 * xss + hh]);
        float x3 = bf2f(xs[(size_t)i3 * xss + hh]);
        EDGE_STEP(x0, a0)
        EDGE_STEP(x1, a1)
        EDGE_STEP(x2, a2)
        EDGE_STEP(x3, a3)
    }
    for (; j < s1; j++) {
        int s = ssrc[j];
        float a = sattr[j];
        float xv = bf2f(xs[(size_t)s * xss + hh]);
        EDGE_STEP(xv, a)
    }
    float agg = (s1 > s0) ? (num / fmaxf(denom, 1e-16f)) : 0.f;
    outb[(size_t)d * Hh + hh] = f2bf(agg + bf2f(xd[(size_t)d * xds + hh]));
#undef EDGE_STEP
}

// ---------------- mean-pool over pre-normed bf16 ----------------

#define PCHUNK 100

__global__ __launch_bounds__(128) void pool_kernel(
    const unsigned short* __restrict__ hb, const int* __restrict__ batch,
    float* __restrict__ pooled, float* __restrict__ cnt) {
    int hh = threadIdx.x;
    int i0 = blockIdx.x * PCHUNK;
    int i1 = min(i0 + PCHUNK, Nn);
    if (i0 >= Nn) return;
    int cur = batch[i0];
    float sum = 0.f, c = 0.f;
    for (int i = i0; i < i1; i++) {
        int gid = batch[i];
        float val = bf2f(hb[(size_t)i * Hh + hh]);
        if (gid != cur) {
            atomicAdd(&pooled[(size_t)cur * Hh + hh], sum);
            if (hh == 0) atomicAdd(&cnt[cur], c);
            cur = gid;
            sum = 0.f;
            c = 0.f;
        }
        sum += val;
        c += 1.f;
    }
    atomicAdd(&pooled[(size_t)cur * Hh + hh], sum);
    if (hh == 0) atomicAdd(&cnt[cur], c);
}

// ---------------- classifier ----------------

__global__ __launch_bounds__(128) void cls_kernel(const float* __restrict__ pooled,
                                                  const float* __restrict__ cnt,
                                                  const float* __restrict__ clinical,
                                                  const float* __restrict__ w,
                                                  const float* __restrict__ bias,
                                                  float* __restrict__ out) {
    int t = threadIdx.x;
    int g = t >> 1, c = t & 1;
    float inv = 1.f / fmaxf(cnt[g], 1.f);
    float s = bias[c];
    for (int j = 0; j < Hh; j++) s += pooled[g * Hh + j] * inv * w[j * NCc + c];
    for (int k = 0; k < Kk; k++) s += clinical[g * Kk + k] * w[(Hh + k) * NCc + c];
    out[g * NCc + c] = s;
}

// ---------------- launch ----------------

extern "C" void kernel_launch(void* const* d_in, const int* in_sizes, int n_in,
                              void* d_out, int out_size, void* d_ws, size_t ws_size,
                              hipStream_t stream) {
    const float* x = (const float*)d_in[0];
    const int* eidx = (const int*)d_in[1];
    const float* eattr = (const float*)d_in[2];
    const int* batch = (const int*)d_in[3];
    const float* clinical = (const float*)d_in[4];
    const float* lin_src_b = (const float*)d_in[6];
    const float* lin_dst_b = (const float*)d_in[8];
    const float* edge_w = (const float*)d_in[9];
    const float* edge_b = (const float*)d_in[10];
    const float* tt = (const float*)d_in[11];
    const float* mlp_b1 = (const float*)d_in[13];
    const float* bn_g = (const float*)d_in[14];
    const float* bn_b = (const float*)d_in[15];
    const float* bn_m = (const float*)d_in[16];
    const float* bn_v = (const float*)d_in[17];
    const float* mlp_b2 = (const float*)d_in[19];
    const float* norm_g = (const float*)d_in[20];
    const float* norm_b = (const float*)d_in[21];
    const float* norm_m = (const float*)d_in[22];
    const float* norm_v = (const float*)d_in[23];
    const float* cls_w = (const float*)d_in[24];
    const float* cls_b = (const float*)d_in[25];
    float* out = (float*)d_out;

    const int* src = eidx;
    const int* dst = eidx + Ee;

    char* ws = (char*)d_ws;
    size_t off_b = 0;
    auto alloc = [&](size_t bytes) -> void* {
        void* p = ws + off_b;
        off_b += (bytes + 255) & ~(size_t)255;
        return p;
    };
    unsigned short* xbf = (unsigned short*)alloc((size_t)Nn * Cc * 2);
    unsigned short* xsd = (unsigned short*)alloc((size_t)Nn * 256 * 2);
    unsigned short* rbuf = (unsigned short*)alloc((size_t)Nn * Hh * 2);
    unsigned short* aggout = (unsigned short*)alloc((size_t)Nn * Hh * 2);
    unsigned short* hmid = (unsigned short*)alloc((size_t)Nn * 2 * Hh * 2);
    unsigned short* pnorm = (unsigned short*)alloc((size_t)Nn * Hh * 2);
    float* hbuf = (float*)alloc((size_t)Nn * Hh * 4);
    int* deg = (int*)alloc((Nn + 1) * 4);
    int* offp = (int*)alloc((Nn + 1) * 4);
    int* pos = (int*)alloc((size_t)Nn * 4);
    int* bsum = (int*)alloc(NB * 4);
    int* boff = (int*)alloc(NB * 4);
    int* ssrc = (int*)alloc((size_t)Ee * 4);
    float* sattr = (float*)alloc((size_t)Ee * 4);
    float* pooled = (float*)alloc((size_t)Gg * Hh * 4);
    float* cntb = (float*)alloc(Gg * 4);
    unsigned short* wt = (unsigned short*)alloc((size_t)327680 * 2);

    hipMemsetAsync(deg, 0, (Nn + 1) * 4, stream);
    hipMemsetAsync(pooled, 0, (size_t)Gg * Hh * 4, stream);
    hipMemsetAsync(cntb, 0, Gg * 4, stream);

    hist_kernel<<<(Ee + 255) / 256, 256, 0, stream>>>(dst, deg);
    bsum_kernel<<<NB, 256, 0, stream>>>(deg, bsum);
    bscan_kernel<<<1, 256, 0, stream>>>(bsum, boff, offp);
    offsets_kernel<<<NB, 256, 0, stream>>>(deg, boff, offp, pos);
    scatter_kernel<<<(Ee + 255) / 256, 256, 0, stream>>>(src, dst, eattr, pos, ssrc, sattr);
    wconv_kernel<<<1280, 256, 0, stream>>>((const float*)d_in[5], (const float*)d_in[7],
                                           (const float*)d_in[12], (const float*)d_in[18], wt);
    xconv_kernel<<<6250, 256, 0, stream>>>(x, xbf);

    const unsigned short* wt_proj = wt;
    const unsigned short* wt_w1 = wt + 65536;
    const unsigned short* wt_w2 = wt + 196608;

    // Fused projection: xsd[:, :128] = x@Wsrc+b, xsd[:, 128:] = x@Wdst+b
    gemm_kernel<<<dim3(4, GY), 256, 0, stream>>>(xbf, wt_proj, lin_src_b, lin_dst_b, nullptr,
                                                 nullptr, nullptr, nullptr, nullptr, xsd, Nn,
                                                 256, Cc, 0);

    for (int l = 0; l < Ll; l++) {
        const unsigned short* cxs;
        const unsigned short* cxd;
        int xss, xds;
        if (l == 0) {
            cxs = xsd;
            xss = 256;
            cxd = xsd + 128;
            xds = 256;
        } else {
            cxs = rbuf;
            xss = Hh;
            cxd = rbuf;
            xds = Hh;
        }
        agg_kernel<<<Nn, 128, 0, stream>>>(cxs, xss, cxd, xds, ssrc, sattr, offp,
                                           edge_w + l * Hh, edge_b + l * Hh, tt + l, aggout);
        // w1: [N,128] @ [128,256] -> hmid (mlp-BN + ReLU, bf16)
        gemm_kernel<<<dim3(4, GY), 256, 0, stream>>>(
            aggout, wt_w1 + (size_t)l * 32768, mlp_b1 + l * 2 * Hh, nullptr,
            bn_g + l * 2 * Hh, bn_b + l * 2 * Hh, bn_m + l * 2 * Hh, bn_v + l * 2 * Hh,
            nullptr, hmid, Nn, 2 * Hh, Hh, 1);
        // w2: [N,256] @ [256,128]; fused residual + next-layer (or final) norm
        int nl = (l == Ll - 1) ? 0 : (l + 1);
        int mode = (l == 0) ? 2 : ((l == Ll - 1) ? 4 : 3);
        unsigned short* outB = (l == Ll - 1) ? pnorm : rbuf;
        gemm_kernel<<<dim3(2, GY), 256, 0, stream>>>(
            hmid, wt_w2 + (size_t)l * 32768, mlp_b2 + l * Hh, nullptr,
            norm_g + nl * Hh, norm_b + nl * Hh, norm_m + nl * Hh, norm_v + nl * Hh,
            hbuf, outB, Nn, Hh, 2 * Hh, mode);
    }

    pool_kernel<<<(Nn + PCHUNK - 1) / PCHUNK, 128, 0, stream>>>(pnorm, batch, pooled, cntb);
    cls_kernel<<<1, 128, 0, stream>>>(pooled, cntb, clinical, cls_w, cls_b, out);
}